// Round 2
// baseline (209.171 us; speedup 1.0000x reference)
//
#include <hip/hip_runtime.h>
#include <hip/hip_bf16.h>

#define B_SZ 8192
#define D_SZ 1024   // elements; == bytes in fp8

typedef __attribute__((ext_vector_type(4))) float floatx4;
typedef __attribute__((ext_vector_type(8))) int   int8v;
typedef __attribute__((ext_vector_type(4))) int   int4v;

__device__ __forceinline__ void glds16(const void* g, void* l) {
    __builtin_amdgcn_global_load_lds(
        (const __attribute__((address_space(1))) void*)g,
        (__attribute__((address_space(3))) void*)l, 16, 0, 0);
}

// One wave per row (rows 0..8191 = img, 8192..16383 = txt). 4 rows/block.
// Also zero-inits the output accumulator (stream-ordered before GEMM atomics).
__global__ __launch_bounds__(256) void norm_cast_fp8(
    const float* __restrict__ img, const float* __restrict__ txt,
    unsigned char* __restrict__ imgQ, unsigned char* __restrict__ txtQ,
    float* __restrict__ out)
{
    if (blockIdx.x == 0 && threadIdx.x == 0) *out = 0.0f;

    const int lane = threadIdx.x & 63;
    int w = blockIdx.x * 4 + (threadIdx.x >> 6);
    const float* src; unsigned char* dst;
    if (w < B_SZ) { src = img + (size_t)w * D_SZ; dst = imgQ + (size_t)w * D_SZ; }
    else { w -= B_SZ; src = txt + (size_t)w * D_SZ; dst = txtQ + (size_t)w * D_SZ; }

    float4 v[4];
    float ss = 0.0f;
    #pragma unroll
    for (int i = 0; i < 4; ++i) {
        v[i] = ((const float4*)src)[lane + 64 * i];
        ss += v[i].x*v[i].x + v[i].y*v[i].y + v[i].z*v[i].z + v[i].w*v[i].w;
    }
    #pragma unroll
    for (int off = 1; off < 64; off <<= 1) ss += __shfl_xor(ss, off, 64);
    const float scale = 1.0f / fmaxf(sqrtf(ss), 1e-12f);

    #pragma unroll
    for (int i = 0; i < 4; ++i) {
        int packed = 0;
        packed = __builtin_amdgcn_cvt_pk_fp8_f32(v[i].x * scale, v[i].y * scale, packed, false);
        packed = __builtin_amdgcn_cvt_pk_fp8_f32(v[i].z * scale, v[i].w * scale, packed, true);
        ((int*)dst)[lane + 64 * i] = packed;
    }
}

#define SCHED0() __builtin_amdgcn_sched_barrier(0)
#define SBAR()   do { SCHED0(); __builtin_amdgcn_s_barrier(); SCHED0(); } while (0)
#define LGKM0()  do { asm volatile("s_waitcnt lgkmcnt(0)" ::: "memory"); SCHED0(); } while (0)

__device__ __forceinline__ int8v cat16(const unsigned char* a, const unsigned char* b) {
    int4v lo = *(const int4v*)a;
    int4v hi = *(const int4v*)b;
    return __builtin_shufflevector(lo, hi, 0, 1, 2, 3, 4, 5, 6, 7);
}

// R12: 256x256 tile, 8 waves (2x4), wave tile 128x64 (8x4 of 16x16x128
// MX-fp8 MFMA). FAITHFUL m201-style 8-phase schedule, adapted to fp8
// (one MFMA covers K=128 -> 4 phases per K-group, 8 MFMA each).
//
// Per K-group g (slots s0=(g&1)*2, s1=s0+1 hold lo/hi 64-B K-halves):
//   p0: ds_read af(mt0-3)+bfr(nt0-1) [12 rd] | BAR | lgkm0 | 8 MFMA | BAR
//   p1: ds_read bfr(nt2-3)           [ 4 rd] | BAR | lgkm0 | 8 MFMA | BAR
//   p2: ds_read af(mt4-7)            [ 8 rd] | BAR | lgkm0 | 8 MFMA | BAR
//   p3: stage HT(2g+4)->s0, HT(2g+5)->s1    | BAR |         8 MFMA |
//       vmcnt(8) | BAR   <- publishes next slot pair workgroup-wide
// Gray-code quadrant order (m0-3n0-1, m0-3n2-3, m4-7n2-3, m4-7n0-1)
// keeps total reads at 24/iter (zero re-reads; bfr01 stays live to p3).
// Each phase's ds_reads sit between the previous trailing barrier and
// this phase's leading barrier -> read latency absorbed by barrier wait.
// p3 stage is safe: p2's trailing barrier guarantees all waves finished
// every read of s0/s1 for this iter. vmcnt(8) before p3's trailing
// barrier leaves exactly this iter's 8 stage-loads in flight (never
// drains to 0 in the main loop); vmcnt(0) at g==6 drains the last pair.
//
// LDS geometry VERBATIM from validated R9-R11 (SQ_LDS_BANK_CONFLICT==0,
// absmax==0): granule swizzle g = p ^ ((row>>1)&3) on the global side,
// fragment reads pos = quad ^ sw retrieve the row-independent
// K-permutation {quad, quad+4}, shared by A and B (K-order invariant).
__global__ __launch_bounds__(512, 2) void siglip_gemm_loss_fp8(
    const unsigned char* __restrict__ A,   // imgQ [B,D] e4m3
    const unsigned char* __restrict__ Bt,  // txtQ [B,D] e4m3
    const float* __restrict__ tp, const float* __restrict__ bp,
    float* __restrict__ out)
{
    __shared__ __align__(16) unsigned char lds[4][32768];  // 128 KB
    __shared__ float red[8];

    const int tid  = threadIdx.x;
    const int lane = tid & 63;
    const int wave = tid >> 6;     // 0..7
    const int wm = wave >> 2;      // 0..1  (row half)
    const int wn = wave & 3;       // 0..3  (col quarter)
    const int quad = lane >> 4;    // 0..3
    const int l16  = lane & 15;
    const int bi = blockIdx.x * 256;
    const int bj = blockIdx.y * 256;

    floatx4 acc[8][4];
    #pragma unroll
    for (int i = 0; i < 8; ++i)
        #pragma unroll
        for (int j = 0; j < 4; ++j)
            acc[i][j] = (floatx4){0.f, 0.f, 0.f, 0.f};

    // Staging addresses (validated): slot s -> row = s>>2, phys p = s&3,
    // global granule = p ^ ((row>>1)&3). LDS dest linear in lane.
    const int s0i = tid, s1i = tid + 512;
    const int r0 = s0i >> 2, g0 = (s0i & 3) ^ ((r0 >> 1) & 3);
    const int r1 = s1i >> 2, g1 = (s1i & 3) ^ ((r1 >> 1) & 3);
    const unsigned offA0 = (unsigned)(bi + r0) * D_SZ + (unsigned)g0 * 16;
    const unsigned offA1 = (unsigned)(bi + r1) * D_SZ + (unsigned)g1 * 16;
    const unsigned offB0 = (unsigned)(bj + r0) * D_SZ + (unsigned)g0 * 16;
    const unsigned offB1 = (unsigned)(bj + r1) * D_SZ + (unsigned)g1 * 16;

    auto stage = [&](int h, int slot) {   // half-K-tile h = K bytes [h*64,h*64+64)
        unsigned char* sb = lds[slot];
        const unsigned ko = (unsigned)h * 64;
        glds16(A  + offA0 + ko, sb + s0i * 16);
        glds16(A  + offA1 + ko, sb + s1i * 16);
        glds16(Bt + offB0 + ko, sb + 16384 + s0i * 16);
        glds16(Bt + offB1 + ko, sb + 16384 + s1i * 16);
    };

    // Fragment read addressing (validated swizzle): pos = quad ^ sw.
    const int sw  = (l16 >> 1) & 3;
    const int pos = quad ^ sw;
    const unsigned aoff = (unsigned)((wm * 128 + l16) * 64 + pos * 16);
    const unsigned boff = (unsigned)(16384 + (wn * 64 + l16) * 64 + pos * 16);

    // Prologue: fill all 4 slots (HT0..3), publish HT0/HT1.
    stage(0, 0); stage(1, 1); stage(2, 2); stage(3, 3);
    asm volatile("s_waitcnt vmcnt(8)" ::: "memory");
    SBAR();

    #define MFMA1(MT, NT, AF) \
        acc[MT][NT] = __builtin_amdgcn_mfma_scale_f32_16x16x128_f8f6f4( \
            AF, bfr[NT], acc[MT][NT], 0, 0, 0, 127, 0, 127)

    #pragma unroll
    for (int g = 0; g < 8; ++g) {
        const int s0 = (g & 1) * 2, s1 = s0 + 1;
        const unsigned char* P0 = lds[s0];   // lo half-K (bytes 128g..+63)
        const unsigned char* P1 = lds[s1];   // hi half-K (bytes 128g+64..+127)

        int8v af[4], bfr[4];

        // ---- phase 0: quadrant m0-3 x n0-1 ------------------------------
        bfr[0] = cat16(P0 + boff,        P1 + boff);
        bfr[1] = cat16(P0 + boff + 1024, P1 + boff + 1024);
        #pragma unroll
        for (int mt = 0; mt < 4; ++mt)
            af[mt] = cat16(P0 + aoff + mt * 1024, P1 + aoff + mt * 1024);
        SBAR();
        LGKM0();
        __builtin_amdgcn_s_setprio(1);
        #pragma unroll
        for (int mt = 0; mt < 4; ++mt) { MFMA1(mt, 0, af[mt]); MFMA1(mt, 1, af[mt]); }
        __builtin_amdgcn_s_setprio(0);
        SBAR();

        // ---- phase 1: quadrant m0-3 x n2-3 ------------------------------
        bfr[2] = cat16(P0 + boff + 2048, P1 + boff + 2048);
        bfr[3] = cat16(P0 + boff + 3072, P1 + boff + 3072);
        SBAR();
        LGKM0();
        __builtin_amdgcn_s_setprio(1);
        #pragma unroll
        for (int mt = 0; mt < 4; ++mt) { MFMA1(mt, 2, af[mt]); MFMA1(mt, 3, af[mt]); }
        __builtin_amdgcn_s_setprio(0);
        SBAR();

        // ---- phase 2: quadrant m4-7 x n2-3 ------------------------------
        #pragma unroll
        for (int mt = 0; mt < 4; ++mt)
            af[mt] = cat16(P0 + aoff + (mt + 4) * 1024, P1 + aoff + (mt + 4) * 1024);
        SBAR();
        LGKM0();
        __builtin_amdgcn_s_setprio(1);
        #pragma unroll
        for (int mt = 0; mt < 4; ++mt) { MFMA1(mt + 4, 2, af[mt]); MFMA1(mt + 4, 3, af[mt]); }
        __builtin_amdgcn_s_setprio(0);
        SBAR();

        // ---- phase 3: stage + quadrant m4-7 x n0-1 ----------------------
        // p2's trailing barrier guarantees every wave finished all its
        // s0/s1 reads for this iter -> restaging s0/s1 is race-free.
        if (g < 6) {
            stage(2 * g + 4, s0);
            stage(2 * g + 5, s1);
        }
        SBAR();
        __builtin_amdgcn_s_setprio(1);
        #pragma unroll
        for (int mt = 0; mt < 4; ++mt) { MFMA1(mt + 4, 0, af[mt]); MFMA1(mt + 4, 1, af[mt]); }
        __builtin_amdgcn_s_setprio(0);
        if (g < 6)       asm volatile("s_waitcnt vmcnt(8)" ::: "memory");
        else if (g == 6) asm volatile("s_waitcnt vmcnt(0)" ::: "memory");
        SBAR();   // publishes next slot pair workgroup-wide
    }
    #undef MFMA1

    // Epilogue: softplus(-label*logit) with hw exp/log, reduce.
    // (Bit-identical to R10/R11 for clean attribution.)
    const float t    = fminf(__expf(tp[0]), 100.0f);
    const float bias = bp[0];
    float lsum = 0.0f;
    #pragma unroll
    for (int mt = 0; mt < 8; ++mt) {
        #pragma unroll
        for (int nt = 0; nt < 4; ++nt) {
            const int jj = bj + wn * 64 + nt * 16 + l16;                // C/D col
            #pragma unroll
            for (int r = 0; r < 4; ++r) {
                const int ii = bi + wm * 128 + mt * 16 + quad * 4 + r;  // C/D row
                float logit = fmaf(acc[mt][nt][r], t, bias);
                float z = (ii == jj) ? logit : -logit;
                float e = __expf(-fabsf(z));
                lsum += fmaxf(-z, 0.0f) + __logf(1.0f + e);
            }
        }
    }
    #pragma unroll
    for (int off = 32; off > 0; off >>= 1) lsum += __shfl_down(lsum, off, 64);

    if (lane == 0) red[wave] = lsum;
    __syncthreads();
    if (tid == 0) {
        float tot = 0.0f;
        #pragma unroll
        for (int i = 0; i < 8; ++i) tot += red[i];
        atomicAdd(out, tot * (1.0f / (float)B_SZ));
    }
}

extern "C" void kernel_launch(void* const* d_in, const int* in_sizes, int n_in,
                              void* d_out, int out_size, void* d_ws, size_t ws_size,
                              hipStream_t stream) {
    const float* img = (const float*)d_in[0];
    const float* txt = (const float*)d_in[1];
    const float* tp  = (const float*)d_in[2];
    const float* bp  = (const float*)d_in[3];
    float* out = (float*)d_out;

    unsigned char* imgQ = (unsigned char*)d_ws;                   // 8 MB
    unsigned char* txtQ = imgQ + (size_t)B_SZ * D_SZ;             // 8 MB

    norm_cast_fp8<<<(2 * B_SZ) / 4, 256, 0, stream>>>(img, txt, imgQ, txtQ, out);
    dim3 grid(B_SZ / 256, B_SZ / 256);
    siglip_gemm_loss_fp8<<<grid, 512, 0, stream>>>(imgQ, txtQ, tp, bp, out);
}

// Round 3
// 199.536 us; speedup vs baseline: 1.0483x; 1.0483x over previous
//
#include <hip/hip_runtime.h>
#include <hip/hip_bf16.h>

#define B_SZ 8192
#define D_SZ 1024   // elements; == bytes in fp8

typedef __attribute__((ext_vector_type(4))) float floatx4;
typedef __attribute__((ext_vector_type(8))) int   int8v;
typedef __attribute__((ext_vector_type(4))) int   int4v;

__device__ __forceinline__ void glds16(const void* g, void* l) {
    __builtin_amdgcn_global_load_lds(
        (const __attribute__((address_space(1))) void*)g,
        (__attribute__((address_space(3))) void*)l, 16, 0, 0);
}

// One wave per row (rows 0..8191 = img, 8192..16383 = txt). 4 rows/block.
// Also zero-inits the output accumulator (stream-ordered before GEMM atomics).
__global__ __launch_bounds__(256) void norm_cast_fp8(
    const float* __restrict__ img, const float* __restrict__ txt,
    unsigned char* __restrict__ imgQ, unsigned char* __restrict__ txtQ,
    float* __restrict__ out)
{
    if (blockIdx.x == 0 && threadIdx.x == 0) *out = 0.0f;

    const int lane = threadIdx.x & 63;
    int w = blockIdx.x * 4 + (threadIdx.x >> 6);
    const float* src; unsigned char* dst;
    if (w < B_SZ) { src = img + (size_t)w * D_SZ; dst = imgQ + (size_t)w * D_SZ; }
    else { w -= B_SZ; src = txt + (size_t)w * D_SZ; dst = txtQ + (size_t)w * D_SZ; }

    float4 v[4];
    float ss = 0.0f;
    #pragma unroll
    for (int i = 0; i < 4; ++i) {
        v[i] = ((const float4*)src)[lane + 64 * i];
        ss += v[i].x*v[i].x + v[i].y*v[i].y + v[i].z*v[i].z + v[i].w*v[i].w;
    }
    #pragma unroll
    for (int off = 1; off < 64; off <<= 1) ss += __shfl_xor(ss, off, 64);
    const float scale = 1.0f / fmaxf(sqrtf(ss), 1e-12f);

    #pragma unroll
    for (int i = 0; i < 4; ++i) {
        int packed = 0;
        packed = __builtin_amdgcn_cvt_pk_fp8_f32(v[i].x * scale, v[i].y * scale, packed, false);
        packed = __builtin_amdgcn_cvt_pk_fp8_f32(v[i].z * scale, v[i].w * scale, packed, true);
        ((int*)dst)[lane + 64 * i] = packed;
    }
}

#define SCHED0() __builtin_amdgcn_sched_barrier(0)
#define SBAR()   do { SCHED0(); __builtin_amdgcn_s_barrier(); SCHED0(); } while (0)
#define LGKM0()  do { asm volatile("s_waitcnt lgkmcnt(0)" ::: "memory"); SCHED0(); } while (0)

__device__ __forceinline__ int8v cat16(const unsigned char* a, const unsigned char* b) {
    int4v lo = *(const int4v*)a;
    int4v hi = *(const int4v*)b;
    return __builtin_shufflevector(lo, hi, 0, 1, 2, 3, 4, 5, 6, 7);
}

// R13: 256x256 tile, 8 waves (2x4), wave tile 128x64 (8x4 of 16x16x128
// MX-fp8 MFMA). R12's 4-phase skeleton with a REGISTER-CLEAN read plan
// (R12 spilled: WRITE_SIZE 39 MB of scratch; af[4]+bfr[4]+in-flight
// reads exceeded the 128 arch-VGPR half of the unified file).
//
// Read plan per K-tile t (slots pair = (t&1)*2, +1; bfr RESIDENT all
// tile, af TRANSIENT pair per phase; worst-case live VGPRs ~104):
//   p0: rd bfr0-3 + af01 [12] | BAR | lgkm0 | 8 MFMA (mt01 x nt0-3) | BAR
//   p1: rd af23           [4] | BAR | lgkm0 | 8 MFMA (mt23)         | BAR
//   p2: rd af45 + af67    [8] | BAR | lgkm0 | 8 MFMA (mt45)         | BAR
//   p3: stage HT(2t+4)->slot0, HT(2t+5)->slot1 ; 8 MFMA (mt67) ;
//       vmcnt(8) | BAR   <- publishes tile t+1 workgroup-wide
// p1/p2 reads sit in the previous phase's trailing shadow (latency
// absorbed while other waves' MFMAs drain). p3 reads NOTHING, so the
// stage into this tile's own slot pair is race-free: p2's trailing
// barrier certifies every wave passed its lgkm0, i.e. all ds_reads of
// this pair COMPLETED, before any stage write can land.
// Ledger (4 glds16/stage-call, verified in R11/R12, absmax 0):
// prologue stages T0,T1 (16 loads), vmcnt(8) publishes T0; p3 of tile t
// stages tile t+2 (t<6) -> gate at end of tile t is vmcnt(8) (t+2's
// loads in flight), vmcnt(0) only at t==6 (drain, free - staged 2
// tiles earlier).
//
// LDS geometry VERBATIM from validated R9-R12 (SQ_LDS_BANK_CONFLICT==0,
// absmax==0): granule swizzle g = p ^ ((row>>1)&3) on the global side,
// fragment reads pos = quad ^ sw retrieve the row-independent
// K-permutation {quad, quad+4}, shared by A and B (K-order invariant).
__global__ __launch_bounds__(512, 2) void siglip_gemm_loss_fp8(
    const unsigned char* __restrict__ A,   // imgQ [B,D] e4m3
    const unsigned char* __restrict__ Bt,  // txtQ [B,D] e4m3
    const float* __restrict__ tp, const float* __restrict__ bp,
    float* __restrict__ out)
{
    __shared__ __align__(16) unsigned char lds[4][32768];  // 128 KB
    __shared__ float red[8];

    const int tid  = threadIdx.x;
    const int lane = tid & 63;
    const int wave = tid >> 6;     // 0..7
    const int wm = wave >> 2;      // 0..1  (row half)
    const int wn = wave & 3;       // 0..3  (col quarter)
    const int quad = lane >> 4;    // 0..3
    const int l16  = lane & 15;
    const int bi = blockIdx.x * 256;
    const int bj = blockIdx.y * 256;

    floatx4 acc[8][4];
    #pragma unroll
    for (int i = 0; i < 8; ++i)
        #pragma unroll
        for (int j = 0; j < 4; ++j)
            acc[i][j] = (floatx4){0.f, 0.f, 0.f, 0.f};

    // Staging addresses (validated): slot s -> row = s>>2, phys p = s&3,
    // global granule = p ^ ((row>>1)&3). LDS dest linear in lane.
    const int s0i = tid, s1i = tid + 512;
    const int r0 = s0i >> 2, g0 = (s0i & 3) ^ ((r0 >> 1) & 3);
    const int r1 = s1i >> 2, g1 = (s1i & 3) ^ ((r1 >> 1) & 3);
    const unsigned offA0 = (unsigned)(bi + r0) * D_SZ + (unsigned)g0 * 16;
    const unsigned offA1 = (unsigned)(bi + r1) * D_SZ + (unsigned)g1 * 16;
    const unsigned offB0 = (unsigned)(bj + r0) * D_SZ + (unsigned)g0 * 16;
    const unsigned offB1 = (unsigned)(bj + r1) * D_SZ + (unsigned)g1 * 16;

    auto stage = [&](int h, int slot) {   // half-K-tile h = K bytes [h*64,h*64+64)
        unsigned char* sb = lds[slot];
        const unsigned ko = (unsigned)h * 64;
        glds16(A  + offA0 + ko, sb + s0i * 16);
        glds16(A  + offA1 + ko, sb + s1i * 16);
        glds16(Bt + offB0 + ko, sb + 16384 + s0i * 16);
        glds16(Bt + offB1 + ko, sb + 16384 + s1i * 16);
    };

    // Fragment read addressing (validated swizzle): pos = quad ^ sw.
    const int sw  = (l16 >> 1) & 3;
    const int pos = quad ^ sw;
    const unsigned aoff = (unsigned)((wm * 128 + l16) * 64 + pos * 16);
    const unsigned boff = (unsigned)(16384 + (wn * 64 + l16) * 64 + pos * 16);

    // Prologue: stage T0 (HT0,1 -> slots 0,1) and T1 (HT2,3 -> 2,3);
    // publish T0 (vmcnt(8): T1's 8 loads stay in flight).
    stage(0, 0); stage(1, 1); stage(2, 2); stage(3, 3);
    asm volatile("s_waitcnt vmcnt(8)" ::: "memory");
    SBAR();

    #define MFMA1(MT, NT, AF) \
        acc[MT][NT] = __builtin_amdgcn_mfma_scale_f32_16x16x128_f8f6f4( \
            AF, bfr[NT], acc[MT][NT], 0, 0, 0, 127, 0, 127)

    #define MFMA_ROWPAIR(MT, AF0, AF1) do { \
        __builtin_amdgcn_s_setprio(1); \
        MFMA1(MT, 0, AF0); MFMA1(MT, 1, AF0); MFMA1(MT, 2, AF0); MFMA1(MT, 3, AF0); \
        MFMA1((MT)+1, 0, AF1); MFMA1((MT)+1, 1, AF1); MFMA1((MT)+1, 2, AF1); MFMA1((MT)+1, 3, AF1); \
        __builtin_amdgcn_s_setprio(0); \
    } while (0)

    #pragma unroll
    for (int t = 0; t < 8; ++t) {
        const int slot0 = (t & 1) * 2, slot1 = slot0 + 1;
        const unsigned char* P0 = lds[slot0];   // lo half-K (bytes 128t..+63)
        const unsigned char* P1 = lds[slot1];   // hi half-K (bytes 128t+64..+127)

        int8v bfr[4];
        int8v afA, afB;

        // ---- p0: bfr0-3 + af01 ; MFMA mt0,1 ----------------------------
        #pragma unroll
        for (int nt = 0; nt < 4; ++nt)
            bfr[nt] = cat16(P0 + boff + nt * 1024, P1 + boff + nt * 1024);
        afA = cat16(P0 + aoff,        P1 + aoff);
        afB = cat16(P0 + aoff + 1024, P1 + aoff + 1024);
        SBAR();
        LGKM0();
        MFMA_ROWPAIR(0, afA, afB);
        SBAR();

        // ---- p1: af23 ; MFMA mt2,3 -------------------------------------
        afA = cat16(P0 + aoff + 2048, P1 + aoff + 2048);
        afB = cat16(P0 + aoff + 3072, P1 + aoff + 3072);
        SBAR();
        LGKM0();
        MFMA_ROWPAIR(2, afA, afB);
        SBAR();

        // ---- p2: af45 + af67 ; MFMA mt4,5 ------------------------------
        afA = cat16(P0 + aoff + 4096, P1 + aoff + 4096);
        afB = cat16(P0 + aoff + 5120, P1 + aoff + 5120);
        int8v afC = cat16(P0 + aoff + 6144, P1 + aoff + 6144);
        int8v afD = cat16(P0 + aoff + 7168, P1 + aoff + 7168);
        SBAR();
        LGKM0();
        MFMA_ROWPAIR(4, afA, afB);
        SBAR();

        // ---- p3: stage (race-free: p2's bar certified all reads of this
        // pair completed) ; MFMA mt6,7 ; counted gate ; publish ----------
        if (t < 6) {
            stage(2 * t + 4, slot0);
            stage(2 * t + 5, slot1);
        }
        MFMA_ROWPAIR(6, afC, afD);
        if (t < 6)       asm volatile("s_waitcnt vmcnt(8)" ::: "memory");
        else if (t == 6) asm volatile("s_waitcnt vmcnt(0)" ::: "memory");
        SBAR();   // publishes tile t+1 workgroup-wide
    }
    #undef MFMA_ROWPAIR
    #undef MFMA1

    // Epilogue: softplus(-label*logit) with hw exp/log, reduce.
    // (Bit-identical to R10-R12 for clean attribution.)
    const float t    = fminf(__expf(tp[0]), 100.0f);
    const float bias = bp[0];
    float lsum = 0.0f;
    #pragma unroll
    for (int mt = 0; mt < 8; ++mt) {
        #pragma unroll
        for (int nt = 0; nt < 4; ++nt) {
            const int jj = bj + wn * 64 + nt * 16 + l16;                // C/D col
            #pragma unroll
            for (int r = 0; r < 4; ++r) {
                const int ii = bi + wm * 128 + mt * 16 + quad * 4 + r;  // C/D row
                float logit = fmaf(acc[mt][nt][r], t, bias);
                float z = (ii == jj) ? logit : -logit;
                float e = __expf(-fabsf(z));
                lsum += fmaxf(-z, 0.0f) + __logf(1.0f + e);
            }
        }
    }
    #pragma unroll
    for (int off = 32; off > 0; off >>= 1) lsum += __shfl_down(lsum, off, 64);

    if (lane == 0) red[wave] = lsum;
    __syncthreads();
    if (tid == 0) {
        float tot = 0.0f;
        #pragma unroll
        for (int i = 0; i < 8; ++i) tot += red[i];
        atomicAdd(out, tot * (1.0f / (float)B_SZ));
    }
}

extern "C" void kernel_launch(void* const* d_in, const int* in_sizes, int n_in,
                              void* d_out, int out_size, void* d_ws, size_t ws_size,
                              hipStream_t stream) {
    const float* img = (const float*)d_in[0];
    const float* txt = (const float*)d_in[1];
    const float* tp  = (const float*)d_in[2];
    const float* bp  = (const float*)d_in[3];
    float* out = (float*)d_out;

    unsigned char* imgQ = (unsigned char*)d_ws;                   // 8 MB
    unsigned char* txtQ = imgQ + (size_t)B_SZ * D_SZ;             // 8 MB

    norm_cast_fp8<<<(2 * B_SZ) / 4, 256, 0, stream>>>(img, txt, imgQ, txtQ, out);
    dim3 grid(B_SZ / 256, B_SZ / 256);
    siglip_gemm_loss_fp8<<<grid, 512, 0, stream>>>(imgQ, txtQ, tp, bp, out);
}